// Round 1
// 59.182 us; speedup vs baseline: 1.0298x; 1.0298x over previous
//
#include <hip/hip_runtime.h>

#define NP 512          // particles
#define BLOCK 512       // threads per block (8 waves); thread = one particle i
#define NDUP 768        // duplicated SoA length (j walks up to jstart+259 <= 767)
constexpr float DIST_EPS = 1e-6f;

__device__ __forceinline__ float waveSum(float v) {
    v += __shfl_down(v, 32, 64);
    v += __shfl_down(v, 16, 64);
    v += __shfl_down(v, 8, 64);
    v += __shfl_down(v, 4, 64);
    v += __shfl_down(v, 2, 64);
    v += __shfl_down(v, 1, 64);
    return v;
}

// Half-pair (Newton) enumeration: thread i covers k = j-i (mod 512) in [1,256],
// k==256 weighted 1/2; block total is doubled at the end. Groups of 4 j's from
// aligned base jstart = i & ~3: g=0 and g=64 need per-element weights, g=1..63
// are mask-free. 4 blocks per batch split the g-range: q0 -> {g0} + [1,16],
// q1 -> [17,32], q2 -> [33,48], q3 -> [49,63] + {g64}.
// 512 blocks x 8 waves = exactly 2 blocks/CU (one residency round, 4 waves/EU),
// launch_bounds(512,4) -> 128-VGPR budget so the unrolled body keeps full ILP.
__global__ __launch_bounds__(BLOCK, 4) void lj_kernel(const float* __restrict__ x,
                                                      float* __restrict__ out) {
    const int b   = blockIdx.x >> 2;    // batch
    const int q   = blockIdx.x & 3;     // g-range slice
    const int tid = threadIdx.x;
    const float* __restrict__ xb = x + b * (NP * 3);

    __shared__ __align__(16) float s[3 * NDUP];  // SoA x|y|z, each 768 (wrap dup)
    __shared__ float red[8 * 5];

    // Stage 1536 floats coalesced, deinterleave xyz -> SoA; fold the wraparound
    // duplicate (first 256 of each dim) into the same pass (p<256 <=> g<768).
    for (int g = tid; g < 3 * NP; g += BLOCK) {
        float v = xb[g];
        int p = g / 3;
        int d = g - p * 3;
        s[d * NDUP + p] = v;
        if (p < 256) s[d * NDUP + NP + p] = v;
    }
    __syncthreads();

    const float* sx = s;
    const float* sy = s + NDUP;
    const float* sz = s + 2 * NDUP;

    const int i      = tid;
    const int m      = i & 3;
    const int jstart = i & ~3;

    const float xi = sx[i], yi = sy[i], zi = sz[i];

    float a0 = 0.f, a1 = 0.f, a2 = 0.f, a3 = 0.f;

    const int gbeg = q * 16 + 1;
    const int gend = (q == 3) ? 63 : q * 16 + 16;

    #pragma unroll 4
    for (int g = gbeg; g <= gend; ++g) {
        const int j = jstart + 4 * g;
        float4 jx = *reinterpret_cast<const float4*>(sx + j);
        float4 jy = *reinterpret_cast<const float4*>(sy + j);
        float4 jz = *reinterpret_cast<const float4*>(sz + j);

        {   // k = 4g+0-m in [1,255]: no mask needed
            float dx = xi - jx.x, dy = yi - jy.x, dz = zi - jz.x;
            float d2 = fmaf(dx, dx, fmaf(dy, dy, fmaf(dz, dz, DIST_EPS)));
            float d6 = d2 * d2 * d2;
            float i6 = __builtin_amdgcn_rcpf(d6);
            a0 = fmaf(i6, i6 - 2.0f, a0);
        }
        {
            float dx = xi - jx.y, dy = yi - jy.y, dz = zi - jz.y;
            float d2 = fmaf(dx, dx, fmaf(dy, dy, fmaf(dz, dz, DIST_EPS)));
            float d6 = d2 * d2 * d2;
            float i6 = __builtin_amdgcn_rcpf(d6);
            a1 = fmaf(i6, i6 - 2.0f, a1);
        }
        {
            float dx = xi - jx.z, dy = yi - jy.z, dz = zi - jz.z;
            float d2 = fmaf(dx, dx, fmaf(dy, dy, fmaf(dz, dz, DIST_EPS)));
            float d6 = d2 * d2 * d2;
            float i6 = __builtin_amdgcn_rcpf(d6);
            a2 = fmaf(i6, i6 - 2.0f, a2);
        }
        {
            float dx = xi - jx.w, dy = yi - jy.w, dz = zi - jz.w;
            float d2 = fmaf(dx, dx, fmaf(dy, dy, fmaf(dz, dz, DIST_EPS)));
            float d6 = d2 * d2 * d2;
            float i6 = __builtin_amdgcn_rcpf(d6);
            a3 = fmaf(i6, i6 - 2.0f, a3);
        }
    }
    float acc = (a0 + a1) + (a2 + a3);

    if (q == 0) {
        // g = 0: j = jstart+e, k = e-m; valid (w=1) iff e > m (k in [1,3])
        #pragma unroll
        for (int e = 0; e < 4; ++e) {
            int j = jstart + e;
            float dx = xi - sx[j], dy = yi - sy[j], dz = zi - sz[j];
            float d2 = fmaf(dx, dx, fmaf(dy, dy, fmaf(dz, dz, DIST_EPS)));
            float d6 = d2 * d2 * d2;
            float i6 = __builtin_amdgcn_rcpf(d6);
            float v = i6 * (i6 - 2.0f);
            acc += (e > m) ? v : 0.f;
        }
    }
    if (q == 3) {
        // g = 64: j = jstart+256+e, k = 256+e-m; w = 1 (k<256), 0.5 (k==256), 0
        #pragma unroll
        for (int e = 0; e < 4; ++e) {
            int j = jstart + 256 + e;
            float dx = xi - sx[j], dy = yi - sy[j], dz = zi - sz[j];
            float d2 = fmaf(dx, dx, fmaf(dy, dy, fmaf(dz, dz, DIST_EPS)));
            float d6 = d2 * d2 * d2;
            float i6 = __builtin_amdgcn_rcpf(d6);
            float v = i6 * (i6 - 2.0f);
            float w = (e < m) ? 1.0f : ((e == m) ? 0.5f : 0.0f);
            acc = fmaf(w, v, acc);
        }
    }

    // Oscillator: only q==0 blocks contribute (thread tid = particle tid).
    float sxs = 0.f, sys = 0.f, szs = 0.f, sqs = 0.f;
    if (q == 0) {
        float px = sx[tid], py = sy[tid], pz = sz[tid];
        sxs = px; sys = py; szs = pz;
        sqs = fmaf(px, px, fmaf(py, py, pz * pz));
    }

    // Block reduction: 8 waves x 5 values
    const int wid  = tid >> 6;
    const int lane = tid & 63;
    float r0 = waveSum(acc);
    float r1 = waveSum(sxs);
    float r2 = waveSum(sys);
    float r3 = waveSum(szs);
    float r4 = waveSum(sqs);
    if (lane == 0) {
        red[wid * 5 + 0] = r0;
        red[wid * 5 + 1] = r1;
        red[wid * 5 + 2] = r2;
        red[wid * 5 + 3] = r3;
        red[wid * 5 + 4] = r4;
    }
    __syncthreads();
    if (tid == 0) {
        float t0 = 0.f, t1 = 0.f, t2 = 0.f, t3 = 0.f, t4 = 0.f;
        #pragma unroll
        for (int w = 0; w < 8; ++w) {
            t0 += red[w * 5 + 0];
            t1 += red[w * 5 + 1];
            t2 += red[w * 5 + 2];
            t3 += red[w * 5 + 3];
            t4 += red[w * 5 + 4];
        }
        float total = 2.0f * t0;   // Newton: unordered-pair sum x2
        if (q == 0) {
            // osc = 0.5 * (sum|x|^2 - |sum x|^2 / N)
            float m2 = (t1 * t1 + t2 * t2 + t3 * t3) * (1.0f / NP);
            total += 0.5f * (t4 - m2);
        }
        atomicAdd(out + b, total);
    }
}

extern "C" void kernel_launch(void* const* d_in, const int* in_sizes, int n_in,
                              void* d_out, int out_size, void* d_ws, size_t ws_size,
                              hipStream_t stream) {
    const float* x = (const float*)d_in[0];
    float* out = (float*)d_out;
    const int B = in_sizes[0] / (NP * 3);   // 128
    // 4 blocks per batch -> 512 blocks, 8 waves each -> 2 blocks/CU, 4 waves/EU.
    lj_kernel<<<dim3(4 * B, 1, 1), BLOCK, 0, stream>>>(x, out);
}